// Round 4
// baseline (2043.574 us; speedup 1.0000x reference)
//
#include <hip/hip_runtime.h>
#include <cstdint>
#include <cstddef>

#define NPTS 500000
#define CIN  128
#define GCH  256
#define COUT 128
#define KTAP 27

typedef __attribute__((ext_vector_type(4))) float    f32x4;
typedef __attribute__((ext_vector_type(2))) float    f32x2;
typedef __attribute__((ext_vector_type(8))) short    s16x8;
typedef __attribute__((ext_vector_type(4))) uint32_t u32x4;
typedef __attribute__((ext_vector_type(2))) uint32_t u32x2;

__device__ __forceinline__ unsigned short f2bf(float f) {
  union { float f; uint32_t u; } v; v.f = f;
  uint32_t r = v.u + 0x7FFFu + ((v.u >> 16) & 1u);
  return (unsigned short)(r >> 16);
}
__device__ __forceinline__ float bf2f(unsigned short h) {
  union { uint32_t u; float f; } v; v.u = ((uint32_t)h) << 16;
  return v.f;
}
__device__ __forceinline__ float bflo(uint32_t u) {
  union { uint32_t u; float f; } v; v.u = u << 16; return v.f;
}
__device__ __forceinline__ float bfhi(uint32_t u) {
  union { uint32_t u; float f; } v; v.u = u & 0xFFFF0000u; return v.f;
}

// ---------- prep: W1 bf16 frags + W2 fp8 frags + zero GRN sums ----------
__global__ __launch_bounds__(256) void k_prep(
    const float* __restrict__ W1, const float* __restrict__ W2,
    unsigned short* __restrict__ W1t, uint8_t* __restrict__ W2t8,
    float* __restrict__ sums) {
  int b = blockIdx.x, t = threadIdx.x;
  if (b == 0 && t < COUT) sums[t] = 0.f;
  int gt = (b & 15) * 256 + t;      // 0..4095
  int grp = gt >> 6, lane = gt & 63;
  int l15 = lane & 15, l4 = lane >> 4;
  if (b < 16) {
    int f = grp >> 2, s = grp & 3;                 // 16 col-tiles x 4 k-steps
    int col = f * 16 + l15, k0 = s * 32 + l4 * 8;
    unsigned short* dst = W1t + gt * 8;
#pragma unroll
    for (int j = 0; j < 8; ++j) dst[j] = f2bf(W1[(size_t)(k0 + j) * GCH + col]);
  } else {
    int f = grp >> 3, s = grp & 7;                 // 8 col-tiles x 8 k-steps
    int col = f * 16 + l15, k0 = s * 32 + l4 * 8;
    float w[8];
#pragma unroll
    for (int e = 0; e < 8; ++e) w[e] = W2[(size_t)(k0 + e) * COUT + col];
    int lo = __builtin_amdgcn_cvt_pk_fp8_f32(w[0], w[1], 0, false);
    lo = __builtin_amdgcn_cvt_pk_fp8_f32(w[2], w[3], lo, true);
    int hi = __builtin_amdgcn_cvt_pk_fp8_f32(w[4], w[5], 0, false);
    hi = __builtin_amdgcn_cvt_pk_fp8_f32(w[6], w[7], hi, true);
    u32x2 q = {(uint32_t)lo, (uint32_t)hi};
    *(u32x2*)(W2t8 + gt * 8) = q;
  }
}

// ---------- K1: h1 = LN(x @ W1 + b1) -> fp8 [N][256], swapped-operand MFMA ----------
// mfma(W1frag, xfrag): lane owns point p = wv*16 + l15, channels c = f*16 + l4*4 + j.
__global__ __launch_bounds__(512) void k_gemm1_ln(
    const float* __restrict__ x, const unsigned short* __restrict__ W1t,
    const float* __restrict__ b1, const float* __restrict__ ln_g,
    const float* __restrict__ ln_b, uint8_t* __restrict__ h1f8) {
  __shared__ unsigned short Al[128][CIN + 8];   // 34.8 KB only -> 2 blocks/CU
  int tid = threadIdx.x, lane = tid & 63, wv = tid >> 6;
  int l15 = lane & 15, l4 = lane >> 4;
  long rowbase = (long)blockIdx.x * 128;

  {                                             // stage x (fp32 -> bf16), read-once
    int ar = tid >> 2, ac = (tid & 3) * 32;
    long gr = rowbase + ar;
    const float* xp = x + gr * CIN + ac;
    bool ok = gr < NPTS;
#pragma unroll
    for (int u = 0; u < 8; ++u) {
      f32x4 v = {0.f, 0.f, 0.f, 0.f};
      if (ok) v = __builtin_nontemporal_load((const f32x4*)(xp + u * 4));
      unsigned short* d = &Al[ar][ac + u * 4];
      d[0] = f2bf(v[0]); d[1] = f2bf(v[1]); d[2] = f2bf(v[2]); d[3] = f2bf(v[3]);
    }
  }
  __syncthreads();

  f32x4 acc[16];
#pragma unroll
  for (int f = 0; f < 16; ++f) acc[f] = (f32x4){0.f, 0.f, 0.f, 0.f};
  s16x8 a[4];
#pragma unroll
  for (int s = 0; s < 4; ++s)
    a[s] = *(const s16x8*)&Al[wv * 16 + l15][s * 32 + l4 * 8];
#pragma unroll
  for (int f = 0; f < 16; ++f)
#pragma unroll
    for (int s = 0; s < 4; ++s) {
      s16x8 w = *(const s16x8*)&W1t[((f * 4 + s) * 64 + lane) * 8];  // L2-hot 64 KB
      acc[f] = __builtin_amdgcn_mfma_f32_16x16x32_bf16(w, a[s], acc[f], 0, 0, 0);
    }

  // + b1, LN over 256 channels: in-lane (16f x 4j) + lanes l15, l15+16, +32, +48
  float s1 = 0.f, s2 = 0.f;
#pragma unroll
  for (int f = 0; f < 16; ++f) {
    f32x4 bb = *(const f32x4*)(b1 + f * 16 + l4 * 4);
#pragma unroll
    for (int j = 0; j < 4; ++j) {
      float v = acc[f][j] + bb[j];
      acc[f][j] = v;
      s1 += v; s2 += v * v;
    }
  }
  s1 += __shfl_xor(s1, 16); s1 += __shfl_xor(s1, 32);
  s2 += __shfl_xor(s2, 16); s2 += __shfl_xor(s2, 32);
  float mu = s1 * (1.f / GCH);
  float var = s2 * (1.f / GCH) - mu * mu;
  float rs = rsqrtf(var + 1e-6f);

  long p = rowbase + wv * 16 + l15;
  bool ok = p < NPTS;
  uint8_t* dp = h1f8 + p * GCH + l4 * 4;
#pragma unroll
  for (int f = 0; f < 16; ++f) {
    f32x4 g4 = *(const f32x4*)(ln_g + f * 16 + l4 * 4);
    f32x4 b4 = *(const f32x4*)(ln_b + f * 16 + l4 * 4);
    float v0 = (acc[f][0] - mu) * rs * g4[0] + b4[0];
    float v1 = (acc[f][1] - mu) * rs * g4[1] + b4[1];
    float v2 = (acc[f][2] - mu) * rs * g4[2] + b4[2];
    float v3 = (acc[f][3] - mu) * rs * g4[3] + b4[3];
    int w0 = __builtin_amdgcn_cvt_pk_fp8_f32(v0, v1, 0, false);
    w0 = __builtin_amdgcn_cvt_pk_fp8_f32(v2, v3, w0, true);
    if (ok) *(uint32_t*)(dp + f * 16) = (uint32_t)w0;   // L2 merges 16B/row chunks
  }
}

// ---------- K2: depthwise gather on fp8 h1 -> fp8 h2, high occupancy ----------
__global__ __launch_bounds__(256) void k_dw(
    const uint8_t* __restrict__ h1f8, const int* __restrict__ nbr,
    const float* __restrict__ dw_w, const float* __restrict__ dw_b,
    uint8_t* __restrict__ h2f8) {
  __shared__ unsigned short wfb[KTAP * 16 * 20];  // [k][l15][20 shorts], 15.5 KB, conflict-free
  __shared__ int idxl[32 * KTAP];                 // 3.4 KB  -> 8 blocks/CU
  int tid = threadIdx.x, lane = tid & 63, wv = tid >> 6;
  int l15 = lane & 15, q = lane >> 4;

  for (int u = tid; u < KTAP * 16; u += 256) {    // stage weights bf16
    int k = u >> 4, c = u & 15;
    const float* wp = dw_w + k * GCH + c * 16;
    unsigned short* d = &wfb[u * 20];
#pragma unroll
    for (int e = 0; e < 16; ++e) d[e] = f2bf(wp[e]);
  }
  size_t pblk = (size_t)blockIdx.x * 32;
  for (int i = tid; i < 32 * KTAP; i += 256)
    idxl[i] = nbr[pblk * KTAP + i];
  __syncthreads();

  f32x2 bias[8];
#pragma unroll
  for (int d = 0; d < 4; ++d) {
    f32x4 b4 = *(const f32x4*)(dw_b + l15 * 16 + d * 4);
    bias[2 * d]     = (f32x2){b4[0], b4[1]};
    bias[2 * d + 1] = (f32x2){b4[2], b4[3]};
  }
  int coff = l15 * 16;

#pragma unroll
  for (int it = 0; it < 2; ++it) {
    int pl = it * 16 + wv * 4 + q;
    f32x2 acc[8];
#pragma unroll
    for (int i = 0; i < 8; ++i) acc[i] = bias[i];
#pragma unroll
    for (int k = 0; k < KTAP; ++k) {
      int row = idxl[pl * KTAP + k];
      u32x4 hv = *(const u32x4*)(h1f8 + ((size_t)(uint32_t)row << 8) + coff);
      const unsigned short* wc = &wfb[(k * 16 + l15) * 20];
#pragma unroll
      for (int j = 0; j < 4; ++j) {
        u32x2 w2 = *(const u32x2*)(wc + j * 4);
        f32x2 lo = __builtin_amdgcn_cvt_pk_f32_fp8(hv[j], false);
        f32x2 hi = __builtin_amdgcn_cvt_pk_f32_fp8(hv[j], true);
        acc[2 * j]     += lo * (f32x2){bflo(w2[0]), bfhi(w2[0])};
        acc[2 * j + 1] += hi * (f32x2){bflo(w2[1]), bfhi(w2[1])};
      }
    }
    u32x4 o;
#pragma unroll
    for (int j = 0; j < 4; ++j) {
      int u = __builtin_amdgcn_cvt_pk_fp8_f32(acc[2 * j][0], acc[2 * j][1], 0, false);
      u = __builtin_amdgcn_cvt_pk_fp8_f32(acc[2 * j + 1][0], acc[2 * j + 1][1], u, true);
      o[j] = (uint32_t)u;
    }
    __builtin_nontemporal_store(o, (u32x4*)(h2f8 + (pblk + pl) * GCH + coff));
  }
}

// ---------- K4: h3 = gelu(h2 @ W2 + b2) bf16 via fp8 MFMA, + per-channel sum(h3^2) ----------
__global__ __launch_bounds__(512) void k_gemm2(
    const uint8_t* __restrict__ h2f8, const uint8_t* __restrict__ W2t8,
    const float* __restrict__ b2, unsigned short* __restrict__ h3,
    float* __restrict__ sums) {
  __shared__ uint8_t Al[128][GCH + 16];   // 34.8 KB -> 2+ blocks/CU
  __shared__ float ssum[COUT];
  int tid = threadIdx.x, lane = tid & 63, wv = tid >> 6;
  int l15 = lane & 15, l4 = lane >> 4;
  long rowbase = (long)blockIdx.x * 128;
  if (tid < COUT) ssum[tid] = 0.f;
  {
    int ar = tid >> 2, ac = (tid & 3) * 64;
    long gr = rowbase + ar;
    const uint8_t* sp = h2f8 + gr * GCH + ac;
    bool ok = gr < NPTS;
    u32x4 z = {0, 0, 0, 0};
#pragma unroll
    for (int u = 0; u < 4; ++u) {
      u32x4 v = z;
      if (ok) v = __builtin_nontemporal_load((const u32x4*)(sp + u * 16));
      *(u32x4*)&Al[ar][ac + u * 16] = v;
    }
  }
  __syncthreads();

  f32x4 acc[8];
#pragma unroll
  for (int f = 0; f < 8; ++f) acc[f] = (f32x4){0.f, 0.f, 0.f, 0.f};
  long aa[8];
#pragma unroll
  for (int s = 0; s < 8; ++s)
    aa[s] = *(const long*)&Al[wv * 16 + l15][s * 32 + l4 * 8];
#pragma unroll
  for (int f = 0; f < 8; ++f)
#pragma unroll
    for (int s = 0; s < 8; ++s) {
      long bb = *(const long*)&W2t8[((f * 8 + s) * 64 + lane) * 8];  // L2-hot 32 KB
      acc[f] = __builtin_amdgcn_mfma_f32_16x16x32_fp8_fp8(aa[s], bb, acc[f], 0, 0, 0);
    }
#pragma unroll
  for (int f = 0; f < 8; ++f) {
    int col = f * 16 + l15;
    float bbv = b2[col];
    float ps = 0.f;
#pragma unroll
    for (int j = 0; j < 4; ++j) {
      long r = rowbase + wv * 16 + l4 * 4 + j;
      float v = acc[f][j] + bbv;
      float g = 0.5f * v * (1.f + erff(v * 0.70710678118654752f));
      if (r < NPTS) {
        h3[r * COUT + col] = f2bf(g);
        ps += g * g;
      }
    }
    ps += __shfl_xor(ps, 16);
    ps += __shfl_xor(ps, 32);
    if (l4 == 0) atomicAdd(&ssum[col], ps);
  }
  __syncthreads();
  if (tid < COUT) atomicAdd(&sums[tid], ssum[tid]);
}

// ---------- K5: GRN finalize -> scale/shift tables ----------
__global__ void k_grn(const float* __restrict__ sums, const float* __restrict__ grn_g,
                      const float* __restrict__ grn_b, float* __restrict__ sAB) {
  __shared__ float gx[COUT];
  __shared__ float mean_s;
  int t = threadIdx.x;
  float g = sqrtf(sums[t]);
  gx[t] = g;
  __syncthreads();
  if (t == 0) {
    float s = 0.f;
    for (int i = 0; i < COUT; ++i) s += gx[i];
    mean_s = s * (1.f / COUT);
  }
  __syncthreads();
  float nx = g / (mean_s + 1e-6f);
  sAB[t] = grn_g[t] * nx + 1.f;
  sAB[COUT + t] = grn_b[t];
}

// ---------- K6: out = h3*sA + sB + x ----------
__global__ __launch_bounds__(256) void k_final(
    const unsigned short* __restrict__ h3, const float* __restrict__ x,
    const float* __restrict__ sAB, float* __restrict__ out) {
  long q = (long)blockIdx.x * 256 + threadIdx.x;
  long idx = q * 4;
  int c0 = (int)(idx & (COUT - 1));
  f32x4 sA = *(const f32x4*)(sAB + c0);
  f32x4 sB = *(const f32x4*)(sAB + COUT + c0);
  ushort4 hv = *(const ushort4*)(h3 + idx);
  f32x4 xv = __builtin_nontemporal_load((const f32x4*)(x + idx));
  f32x4 r;
  r[0] = bf2f(hv.x) * sA[0] + sB[0] + xv[0];
  r[1] = bf2f(hv.y) * sA[1] + sB[1] + xv[1];
  r[2] = bf2f(hv.z) * sA[2] + sB[2] + xv[2];
  r[3] = bf2f(hv.w) * sA[3] + sB[3] + xv[3];
  __builtin_nontemporal_store(r, (f32x4*)(out + idx));
}

extern "C" void kernel_launch(void* const* d_in, const int* in_sizes, int n_in,
                              void* d_out, int out_size, void* d_ws, size_t ws_size,
                              hipStream_t stream) {
  const float* x     = (const float*)d_in[0];
  const int*   nbr   = (const int*)d_in[1];
  const float* W1    = (const float*)d_in[2];
  const float* b1    = (const float*)d_in[3];
  const float* ln_g  = (const float*)d_in[4];
  const float* ln_b  = (const float*)d_in[5];
  const float* dw_w  = (const float*)d_in[6];
  const float* dw_b  = (const float*)d_in[7];
  const float* W2    = (const float*)d_in[8];
  const float* b2    = (const float*)d_in[9];
  const float* grn_g = (const float*)d_in[10];
  const float* grn_b = (const float*)d_in[11];
  float* out = (float*)d_out;

  char* ws = (char*)d_ws;
  uint8_t* h1f8       = (uint8_t*)ws;                                // 128 MB
  unsigned short* h3  = (unsigned short*)(ws + (size_t)NPTS * GCH);  // 128 MB
  size_t off = (size_t)NPTS * GCH * 2;
  unsigned short* W1t = (unsigned short*)(ws + off);                 // 64 KB
  uint8_t* W2t8       = (uint8_t*)(ws + off + 65536);                // 32 KB
  float* sums         = (float*)(ws + off + 65536 + 32768);
  float* sAB          = (float*)(ws + off + 65536 + 32768 + 512);
  uint8_t* h2f8       = (uint8_t*)d_out;                             // 128 MB in d_out

  k_prep<<<32, 256, 0, stream>>>(W1, W2, W1t, W2t8, sums);
  k_gemm1_ln<<<(NPTS + 127) / 128, 512, 0, stream>>>(x, W1t, b1, ln_g, ln_b, h1f8);
  k_dw<<<NPTS / 32, 256, 0, stream>>>(h1f8, nbr, dw_w, dw_b, h2f8);
  k_gemm2<<<(NPTS + 127) / 128, 512, 0, stream>>>(h2f8, W2t8, b2, h3, sums);
  k_grn<<<1, COUT, 0, stream>>>(sums, grn_g, grn_b, sAB);
  k_final<<<(NPTS * COUT / 4) / 256, 256, 0, stream>>>(h3, x, sAB, out);
}

// Round 5
// 1131.671 us; speedup vs baseline: 1.8058x; 1.8058x over previous
//
#include <hip/hip_runtime.h>
#include <cstdint>
#include <cstddef>

#define NPTS 500000
#define CIN  128
#define GCH  256
#define COUT 128
#define KTAP 27

typedef __attribute__((ext_vector_type(4))) float    f32x4;
typedef __attribute__((ext_vector_type(2))) float    f32x2;
typedef __attribute__((ext_vector_type(8))) short    s16x8;
typedef __attribute__((ext_vector_type(4))) uint32_t u32x4;
typedef __attribute__((ext_vector_type(2))) uint32_t u32x2;

__device__ __forceinline__ unsigned short f2bf(float f) {
  union { float f; uint32_t u; } v; v.f = f;
  uint32_t r = v.u + 0x7FFFu + ((v.u >> 16) & 1u);
  return (unsigned short)(r >> 16);
}
__device__ __forceinline__ float bf2f(unsigned short h) {
  union { uint32_t u; float f; } v; v.u = ((uint32_t)h) << 16;
  return v.f;
}

// ---------- prep: W1 bf16 frags + W2 fp8 frags + zero GRN sums ----------
__global__ __launch_bounds__(256) void k_prep(
    const float* __restrict__ W1, const float* __restrict__ W2,
    unsigned short* __restrict__ W1t, uint8_t* __restrict__ W2t8,
    float* __restrict__ sums) {
  int b = blockIdx.x, t = threadIdx.x;
  if (b == 0 && t < COUT) sums[t] = 0.f;
  int gt = (b & 15) * 256 + t;      // 0..4095
  int grp = gt >> 6, lane = gt & 63;
  int l15 = lane & 15, l4 = lane >> 4;
  if (b < 16) {
    int f = grp >> 2, s = grp & 3;                 // 16 col-tiles x 4 k-steps
    int col = f * 16 + l15, k0 = s * 32 + l4 * 8;
    unsigned short* dst = W1t + gt * 8;
#pragma unroll
    for (int j = 0; j < 8; ++j) dst[j] = f2bf(W1[(size_t)(k0 + j) * GCH + col]);
  } else {
    int f = grp >> 3, s = grp & 7;                 // 8 col-tiles x 8 k-steps
    int col = f * 16 + l15, k0 = s * 32 + l4 * 8;
    float w[8];
#pragma unroll
    for (int e = 0; e < 8; ++e) w[e] = W2[(size_t)(k0 + e) * COUT + col];
    int lo = __builtin_amdgcn_cvt_pk_fp8_f32(w[0], w[1], 0, false);
    lo = __builtin_amdgcn_cvt_pk_fp8_f32(w[2], w[3], lo, true);
    int hi = __builtin_amdgcn_cvt_pk_fp8_f32(w[4], w[5], 0, false);
    hi = __builtin_amdgcn_cvt_pk_fp8_f32(w[6], w[7], hi, true);
    u32x2 q = {(uint32_t)lo, (uint32_t)hi};
    *(u32x2*)(W2t8 + gt * 8) = q;
  }
}

// ---------- K1: h1 = LN(x @ W1 + b1) -> fp8 [N][256], swapped-operand MFMA ----------
__global__ __launch_bounds__(512) void k_gemm1_ln(
    const float* __restrict__ x, const unsigned short* __restrict__ W1t,
    const float* __restrict__ b1, const float* __restrict__ ln_g,
    const float* __restrict__ ln_b, uint8_t* __restrict__ h1f8) {
  __shared__ unsigned short Al[128][CIN + 8];   // 34.8 KB
  int tid = threadIdx.x, lane = tid & 63, wv = tid >> 6;
  int l15 = lane & 15, l4 = lane >> 4;
  long rowbase = (long)blockIdx.x * 128;

  {                                             // stage x (fp32 -> bf16), read-once
    int ar = tid >> 2, ac = (tid & 3) * 32;
    long gr = rowbase + ar;
    const float* xp = x + gr * CIN + ac;
    bool ok = gr < NPTS;
#pragma unroll
    for (int u = 0; u < 8; ++u) {
      f32x4 v = {0.f, 0.f, 0.f, 0.f};
      if (ok) v = __builtin_nontemporal_load((const f32x4*)(xp + u * 4));
      unsigned short* d = &Al[ar][ac + u * 4];
      d[0] = f2bf(v[0]); d[1] = f2bf(v[1]); d[2] = f2bf(v[2]); d[3] = f2bf(v[3]);
    }
  }
  __syncthreads();

  f32x4 acc[16];
#pragma unroll
  for (int f = 0; f < 16; ++f) acc[f] = (f32x4){0.f, 0.f, 0.f, 0.f};
  s16x8 a[4];
#pragma unroll
  for (int s = 0; s < 4; ++s)
    a[s] = *(const s16x8*)&Al[wv * 16 + l15][s * 32 + l4 * 8];
#pragma unroll
  for (int f = 0; f < 16; ++f)
#pragma unroll
    for (int s = 0; s < 4; ++s) {
      s16x8 w = *(const s16x8*)&W1t[((f * 4 + s) * 64 + lane) * 8];  // L2-hot 64 KB
      acc[f] = __builtin_amdgcn_mfma_f32_16x16x32_bf16(w, a[s], acc[f], 0, 0, 0);
    }

  float s1 = 0.f, s2 = 0.f;
#pragma unroll
  for (int f = 0; f < 16; ++f) {
    f32x4 bb = *(const f32x4*)(b1 + f * 16 + l4 * 4);
#pragma unroll
    for (int j = 0; j < 4; ++j) {
      float v = acc[f][j] + bb[j];
      acc[f][j] = v;
      s1 += v; s2 += v * v;
    }
  }
  s1 += __shfl_xor(s1, 16); s1 += __shfl_xor(s1, 32);
  s2 += __shfl_xor(s2, 16); s2 += __shfl_xor(s2, 32);
  float mu = s1 * (1.f / GCH);
  float var = s2 * (1.f / GCH) - mu * mu;
  float rs = rsqrtf(var + 1e-6f);

  long p = rowbase + wv * 16 + l15;
  bool ok = p < NPTS;
  uint8_t* dp = h1f8 + p * GCH + l4 * 4;
#pragma unroll
  for (int f = 0; f < 16; ++f) {
    f32x4 g4 = *(const f32x4*)(ln_g + f * 16 + l4 * 4);
    f32x4 b4 = *(const f32x4*)(ln_b + f * 16 + l4 * 4);
    float v0 = (acc[f][0] - mu) * rs * g4[0] + b4[0];
    float v1 = (acc[f][1] - mu) * rs * g4[1] + b4[1];
    float v2 = (acc[f][2] - mu) * rs * g4[2] + b4[2];
    float v3 = (acc[f][3] - mu) * rs * g4[3] + b4[3];
    int w0 = __builtin_amdgcn_cvt_pk_fp8_f32(v0, v1, 0, false);
    w0 = __builtin_amdgcn_cvt_pk_fp8_f32(v2, v3, w0, true);
    if (ok) *(uint32_t*)(dp + f * 16) = (uint32_t)w0;
  }
}

// ---------- K2: depthwise gather on fp8 h1 -> fp8 h2 ----------
// 512 threads = 8 waves, 64 points/block: LDS 34.5 KB -> 4 blocks/CU -> 32 waves = 100%.
// f32 weights in LDS (r3-proven layout, no invariant-hoist register blowup).
__global__ __launch_bounds__(512) void k_dw(
    const uint8_t* __restrict__ h1f8, const int* __restrict__ nbr,
    const float* __restrict__ dw_w, const float* __restrict__ dw_b,
    uint8_t* __restrict__ h2f8) {
  __shared__ float wf[KTAP * 4 * 16 * 4];   // [k][j][l15][4] f32, 27648 B, conflict-free
  __shared__ int idxl[64 * KTAP];           // 6912 B
  int tid = threadIdx.x, lane = tid & 63, wv = tid >> 6;
  int l15 = lane & 15, q = lane >> 4;

  for (int u = tid; u < KTAP * 64; u += 512) {   // stage weights f32
    int g = u >> 4, ld = u & 15, k = g >> 2, j = g & 3;
    f32x4 w4 = *(const f32x4*)(dw_w + k * GCH + ld * 16 + j * 4);
    *(f32x4*)&wf[u * 4] = w4;
  }
  size_t pblk = (size_t)blockIdx.x * 64;
  for (int i = tid; i < 64 * KTAP; i += 512) {   // stage indices (guard tail block)
    size_t gi = pblk * KTAP + i;
    idxl[i] = (gi < (size_t)NPTS * KTAP) ? nbr[gi] : 0;
  }
  __syncthreads();

  f32x2 bias[8];
#pragma unroll
  for (int d = 0; d < 4; ++d) {
    f32x4 b4 = *(const f32x4*)(dw_b + l15 * 16 + d * 4);
    bias[2 * d]     = (f32x2){b4[0], b4[1]};
    bias[2 * d + 1] = (f32x2){b4[2], b4[3]};
  }
  int coff = l15 * 16;   // byte offset in 256-B fp8 row

#pragma unroll
  for (int it = 0; it < 2; ++it) {
    int pl = it * 32 + wv * 4 + q;               // 0..63
    size_t p = pblk + pl;
    f32x2 acc[8];
#pragma unroll
    for (int i = 0; i < 8; ++i) acc[i] = bias[i];
#pragma unroll
    for (int k = 0; k < KTAP; ++k) {
      int row = idxl[pl * KTAP + k];                       // LDS broadcast per 16-lane group
      const uint8_t* sp = h1f8 + ((size_t)(uint32_t)row << 8) + coff;
      u32x4 hv = *(const u32x4*)sp;                        // 16 fp8 channels
#pragma unroll
      for (int j = 0; j < 4; ++j) {
        f32x4 w4 = *(const f32x4*)&wf[((k * 4 + j) * 16 + l15) * 4];
        f32x2 lo = __builtin_amdgcn_cvt_pk_f32_fp8(hv[j], false);
        f32x2 hi = __builtin_amdgcn_cvt_pk_f32_fp8(hv[j], true);
        acc[2 * j]     += lo * (f32x2){w4[0], w4[1]};
        acc[2 * j + 1] += hi * (f32x2){w4[2], w4[3]};
      }
    }
    u32x4 o;
#pragma unroll
    for (int j = 0; j < 4; ++j) {
      int u = __builtin_amdgcn_cvt_pk_fp8_f32(acc[2 * j][0], acc[2 * j][1], 0, false);
      u = __builtin_amdgcn_cvt_pk_fp8_f32(acc[2 * j + 1][0], acc[2 * j + 1][1], u, true);
      o[j] = (uint32_t)u;
    }
    if (p < NPTS)
      __builtin_nontemporal_store(o, (u32x4*)(h2f8 + p * GCH + coff));
  }
}

// ---------- K4: h3 = gelu(h2 @ W2 + b2) bf16 via fp8 MFMA, + per-channel sum(h3^2) ----------
__global__ __launch_bounds__(512) void k_gemm2(
    const uint8_t* __restrict__ h2f8, const uint8_t* __restrict__ W2t8,
    const float* __restrict__ b2, unsigned short* __restrict__ h3,
    float* __restrict__ sums) {
  __shared__ uint8_t Al[128][GCH + 16];   // 34.8 KB
  __shared__ float ssum[COUT];
  int tid = threadIdx.x, lane = tid & 63, wv = tid >> 6;
  int l15 = lane & 15, l4 = lane >> 4;
  long rowbase = (long)blockIdx.x * 128;
  if (tid < COUT) ssum[tid] = 0.f;
  {
    int ar = tid >> 2, ac = (tid & 3) * 64;
    long gr = rowbase + ar;
    const uint8_t* sp = h2f8 + gr * GCH + ac;
    bool ok = gr < NPTS;
    u32x4 z = {0, 0, 0, 0};
#pragma unroll
    for (int u = 0; u < 4; ++u) {
      u32x4 v = z;
      if (ok) v = __builtin_nontemporal_load((const u32x4*)(sp + u * 16));
      *(u32x4*)&Al[ar][ac + u * 16] = v;
    }
  }
  __syncthreads();

  f32x4 acc[8];
#pragma unroll
  for (int f = 0; f < 8; ++f) acc[f] = (f32x4){0.f, 0.f, 0.f, 0.f};
  long aa[8];
#pragma unroll
  for (int s = 0; s < 8; ++s)
    aa[s] = *(const long*)&Al[wv * 16 + l15][s * 32 + l4 * 8];
#pragma unroll
  for (int f = 0; f < 8; ++f)
#pragma unroll
    for (int s = 0; s < 8; ++s) {
      long bb = *(const long*)&W2t8[((f * 8 + s) * 64 + lane) * 8];  // L2-hot 32 KB
      acc[f] = __builtin_amdgcn_mfma_f32_16x16x32_fp8_fp8(aa[s], bb, acc[f], 0, 0, 0);
    }
#pragma unroll
  for (int f = 0; f < 8; ++f) {
    int col = f * 16 + l15;
    float bbv = b2[col];
    float ps = 0.f;
#pragma unroll
    for (int j = 0; j < 4; ++j) {
      long r = rowbase + wv * 16 + l4 * 4 + j;
      float v = acc[f][j] + bbv;
      float g = 0.5f * v * (1.f + erff(v * 0.70710678118654752f));
      if (r < NPTS) {
        h3[r * COUT + col] = f2bf(g);
        ps += g * g;
      }
    }
    ps += __shfl_xor(ps, 16);
    ps += __shfl_xor(ps, 32);
    if (l4 == 0) atomicAdd(&ssum[col], ps);
  }
  __syncthreads();
  if (tid < COUT) atomicAdd(&sums[tid], ssum[tid]);
}

// ---------- K5: GRN finalize -> scale/shift tables ----------
__global__ void k_grn(const float* __restrict__ sums, const float* __restrict__ grn_g,
                      const float* __restrict__ grn_b, float* __restrict__ sAB) {
  __shared__ float gx[COUT];
  __shared__ float mean_s;
  int t = threadIdx.x;
  float g = sqrtf(sums[t]);
  gx[t] = g;
  __syncthreads();
  if (t == 0) {
    float s = 0.f;
    for (int i = 0; i < COUT; ++i) s += gx[i];
    mean_s = s * (1.f / COUT);
  }
  __syncthreads();
  float nx = g / (mean_s + 1e-6f);
  sAB[t] = grn_g[t] * nx + 1.f;
  sAB[COUT + t] = grn_b[t];
}

// ---------- K6: out = h3*sA + sB + x ----------
__global__ __launch_bounds__(256) void k_final(
    const unsigned short* __restrict__ h3, const float* __restrict__ x,
    const float* __restrict__ sAB, float* __restrict__ out) {
  long q = (long)blockIdx.x * 256 + threadIdx.x;
  long idx = q * 4;
  int c0 = (int)(idx & (COUT - 1));
  f32x4 sA = *(const f32x4*)(sAB + c0);
  f32x4 sB = *(const f32x4*)(sAB + COUT + c0);
  ushort4 hv = *(const ushort4*)(h3 + idx);
  f32x4 xv = __builtin_nontemporal_load((const f32x4*)(x + idx));
  f32x4 r;
  r[0] = bf2f(hv.x) * sA[0] + sB[0] + xv[0];
  r[1] = bf2f(hv.y) * sA[1] + sB[1] + xv[1];
  r[2] = bf2f(hv.z) * sA[2] + sB[2] + xv[2];
  r[3] = bf2f(hv.w) * sA[3] + sB[3] + xv[3];
  __builtin_nontemporal_store(r, (f32x4*)(out + idx));
}

extern "C" void kernel_launch(void* const* d_in, const int* in_sizes, int n_in,
                              void* d_out, int out_size, void* d_ws, size_t ws_size,
                              hipStream_t stream) {
  const float* x     = (const float*)d_in[0];
  const int*   nbr   = (const int*)d_in[1];
  const float* W1    = (const float*)d_in[2];
  const float* b1    = (const float*)d_in[3];
  const float* ln_g  = (const float*)d_in[4];
  const float* ln_b  = (const float*)d_in[5];
  const float* dw_w  = (const float*)d_in[6];
  const float* dw_b  = (const float*)d_in[7];
  const float* W2    = (const float*)d_in[8];
  const float* b2    = (const float*)d_in[9];
  const float* grn_g = (const float*)d_in[10];
  const float* grn_b = (const float*)d_in[11];
  float* out = (float*)d_out;

  char* ws = (char*)d_ws;
  uint8_t* h1f8       = (uint8_t*)ws;                                // 128 MB
  unsigned short* h3  = (unsigned short*)(ws + (size_t)NPTS * GCH);  // 128 MB
  size_t off = (size_t)NPTS * GCH * 2;
  unsigned short* W1t = (unsigned short*)(ws + off);                 // 64 KB
  uint8_t* W2t8       = (uint8_t*)(ws + off + 65536);                // 32 KB
  float* sums         = (float*)(ws + off + 65536 + 32768);
  float* sAB          = (float*)(ws + off + 65536 + 32768 + 512);
  uint8_t* h2f8       = (uint8_t*)d_out;                             // 128 MB in d_out

  k_prep<<<32, 256, 0, stream>>>(W1, W2, W1t, W2t8, sums);
  k_gemm1_ln<<<(NPTS + 127) / 128, 512, 0, stream>>>(x, W1t, b1, ln_g, ln_b, h1f8);
  k_dw<<<(NPTS + 63) / 64, 512, 0, stream>>>(h1f8, nbr, dw_w, dw_b, h2f8);
  k_gemm2<<<(NPTS + 127) / 128, 512, 0, stream>>>(h2f8, W2t8, b2, h3, sums);
  k_grn<<<1, COUT, 0, stream>>>(sums, grn_g, grn_b, sAB);
  k_final<<<(NPTS * COUT / 4) / 256, 256, 0, stream>>>(h3, x, sAB, out);
}